// Round 1
// baseline (1752.226 us; speedup 1.0000x reference)
//
#include <hip/hip_runtime.h>
#include <cstdio>
#include <cstdint>

typedef __bf16 bf16_t;
typedef __bf16 bf16x8 __attribute__((ext_vector_type(8)));
typedef __bf16 bf16x4 __attribute__((ext_vector_type(4)));
typedef float  f32x4  __attribute__((ext_vector_type(4)));

// problem dims
#define B_ROWS 8192
#define GEN    5000
#define GENP   5120   // padded K for gemm1 / N for gemm_m
#define H1     4128
#define H1P    4224
#define H2     2064
#define H2P    2176
#define LT     1032
#define LTP    1152

// ---------------- async global->LDS helper ----------------
__device__ __forceinline__ void load_lds16(const bf16_t* g, bf16_t* l) {
  __builtin_amdgcn_global_load_lds((__attribute__((address_space(1))) void*)g,
                                   (__attribute__((address_space(3))) void*)l,
                                   16, 0, 0);
}

// ---------------- GEMM: C = A (MxK) * B^T (NxK), bf16 in, f32 acc ----------------
// MODE 0: store C as bf16 (ld Npad) + atomic per-column sum/sumsq (for BN stats)
// MODE 1: store C as f32 to Cf with column bound Nvalid (ld Nvalid)
template<int MODE>
__global__ __launch_bounds__(256, 2)
void gemm_bt(const bf16_t* __restrict__ A, const bf16_t* __restrict__ Bm,
             int K, bf16_t* __restrict__ Cb, int Npad,
             float* __restrict__ sum, float* __restrict__ sq,
             float* __restrict__ Cf, int Nvalid)
{
  __shared__ bf16_t As[128 * 64];
  __shared__ bf16_t Bs[128 * 64];
  const int tid  = threadIdx.x;
  const int wave = tid >> 6;
  const int lane = tid & 63;
  const int brow = blockIdx.y * 128;
  const int bcol = blockIdx.x * 128;
  const int wrow = (wave >> 1) * 64;
  const int wcol = (wave & 1) * 64;

  // staging decomposition: 8 threads per 64-elem row, 16B per thread
  const int rr = tid >> 3;        // 0..31
  const int cc = (tid & 7) * 8;   // 0..56

  const bf16_t* ga[4];
  const bf16_t* gb[4];
#pragma unroll
  for (int i = 0; i < 4; ++i) {
    ga[i] = A  + (size_t)(brow + i * 32 + rr) * K + cc;
    gb[i] = Bm + (size_t)(bcol + i * 32 + rr) * K + cc;
  }
  bf16_t* lab = As + wave * 512;  // wave-uniform LDS base (lane*16B appended by HW)
  bf16_t* lbb = Bs + wave * 512;

  f32x4 acc[4][4] = {};

  const int lr   = lane & 15;
  const int ksel = (lane >> 4) * 8;

  for (int kt = 0; kt < K; kt += 64) {
#pragma unroll
    for (int i = 0; i < 4; ++i) {
      load_lds16(ga[i] + kt, lab + i * 2048);
      load_lds16(gb[i] + kt, lbb + i * 2048);
    }
    __syncthreads();
#pragma unroll
    for (int kk = 0; kk < 2; ++kk) {
      bf16x8 af[4], bfr[4];
#pragma unroll
      for (int mi = 0; mi < 4; ++mi)
        af[mi] = *(const bf16x8*)(As + (wrow + mi * 16 + lr) * 64 + kk * 32 + ksel);
#pragma unroll
      for (int ni = 0; ni < 4; ++ni)
        bfr[ni] = *(const bf16x8*)(Bs + (wcol + ni * 16 + lr) * 64 + kk * 32 + ksel);
#pragma unroll
      for (int mi = 0; mi < 4; ++mi)
#pragma unroll
        for (int ni = 0; ni < 4; ++ni)
          acc[mi][ni] = __builtin_amdgcn_mfma_f32_16x16x32_bf16(af[mi], bfr[ni], acc[mi][ni], 0, 0, 0);
    }
    __syncthreads();
  }

  // epilogue: C/D layout col=lane&15, row=(lane>>4)*4+reg  [guide §3, m89-verified]
  const int lcol = lane & 15;
  const int lrow = (lane >> 4) * 4;
  if (MODE == 0) {
#pragma unroll
    for (int ni = 0; ni < 4; ++ni) {
      const int colg = bcol + wcol + ni * 16 + lcol;
      float s = 0.f, s2 = 0.f;
#pragma unroll
      for (int mi = 0; mi < 4; ++mi) {
        const int rowg = brow + wrow + mi * 16 + lrow;
#pragma unroll
        for (int r = 0; r < 4; ++r) {
          float v = acc[mi][ni][r];
          s += v; s2 += v * v;
          Cb[(size_t)(rowg + r) * Npad + colg] = (bf16_t)v;
        }
      }
      // reduce over the 4 lane-groups sharing this column (rows of the 64-row wave tile)
      s  += __shfl_xor(s, 16, 64);  s  += __shfl_xor(s, 32, 64);
      s2 += __shfl_xor(s2, 16, 64); s2 += __shfl_xor(s2, 32, 64);
      if (lane < 16) {
        atomicAdd(&sum[colg], s);
        atomicAdd(&sq[colg], s2);
      }
    }
  } else {
#pragma unroll
    for (int ni = 0; ni < 4; ++ni) {
      const int colg = bcol + wcol + ni * 16 + lcol;
      if (colg < Nvalid) {
#pragma unroll
        for (int mi = 0; mi < 4; ++mi) {
          const int rowg = brow + wrow + mi * 16 + lrow;
#pragma unroll
          for (int r = 0; r < 4; ++r)
            Cf[(size_t)(rowg + r) * Nvalid + colg] = acc[mi][ni][r];
        }
      }
    }
  }
}

// ---------------- prep: out[npad][kpad] = bf16(W*mask), zero-padded ----------------
__global__ void k_prep(const float* __restrict__ W, const float* __restrict__ Mk,
                       bf16_t* __restrict__ out, int N, int K, int Npad, int Kpad)
{
  const int  kg    = Kpad >> 3;
  const long total = (long)Npad * kg;
  for (long idx = (long)blockIdx.x * blockDim.x + threadIdx.x; idx < total;
       idx += (long)gridDim.x * blockDim.x) {
    const int n = (int)(idx / kg);
    const int c = (int)(idx % kg) * 8;
    bf16x8 o;
#pragma unroll
    for (int j = 0; j < 8; ++j) o[j] = (bf16_t)0.f;
    if (n < N && c < K) {               // K % 8 == 0 for all inputs
      const f32x4* w4 = (const f32x4*)(W + (size_t)n * K + c);
      f32x4 a = w4[0], b = w4[1];
      if (Mk) {
        const f32x4* m4 = (const f32x4*)(Mk + (size_t)n * K + c);
        f32x4 ma = m4[0], mb = m4[1];
        a *= ma; b *= mb;
      }
#pragma unroll
      for (int j = 0; j < 4; ++j) { o[j] = (bf16_t)a[j]; o[4 + j] = (bf16_t)b[j]; }
    }
    *(bf16x8*)(out + (size_t)idx * 8) = o;
  }
}

// ---------------- BN finalize: sum->scale, sq->shift ----------------
__global__ void k_finalize(float* __restrict__ sum, float* __restrict__ sq,
                           const float* __restrict__ g, const float* __restrict__ be,
                           int Nvalid, int Npad)
{
  const int c = blockIdx.x * blockDim.x + threadIdx.x;
  if (c >= Npad) return;
  float sc = 0.f, sh = 0.f;
  if (c < Nvalid) {
    const float invM = 1.0f / 8192.0f;
    float mean = sum[c] * invM;
    float var  = sq[c] * invM - mean * mean;
    sc = g[c] * rsqrtf(var + 1e-3f);
    sh = be[c] - mean * sc;
  }
  sum[c] = sc; sq[c] = sh;
}

// ---------------- BN apply (+optional ELU, optional f32 out) ----------------
__global__ void k_bn_elu(const bf16_t* __restrict__ pre, const float* __restrict__ sc,
                         const float* __restrict__ sh, bf16_t* __restrict__ outb,
                         float* __restrict__ outf, int Nvalid, int Npad, int elu)
{
  const int  ng    = Npad >> 3;
  const long total = (long)B_ROWS * ng;
  for (long idx = (long)blockIdx.x * blockDim.x + threadIdx.x; idx < total;
       idx += (long)gridDim.x * blockDim.x) {
    const int r = (int)(idx / ng);
    const int c = (int)(idx % ng) * 8;
    bf16x8 o;
#pragma unroll
    for (int j = 0; j < 8; ++j) o[j] = (bf16_t)0.f;
    if (c < Nvalid) {                   // Nvalid % 8 == 0 -> group fully valid
      bf16x8 x = *(const bf16x8*)(pre + (size_t)r * Npad + c);
      f32x4 y0, y1;
#pragma unroll
      for (int j = 0; j < 8; ++j) {
        float v = (float)x[j] * sc[c + j] + sh[c + j];
        if (elu) v = v > 0.f ? v : expm1f(v);
        if (j < 4) y0[j] = v; else y1[j - 4] = v;
        o[j] = (bf16_t)v;
      }
      if (outf) {
        float* p = outf + (size_t)r * Nvalid + c;
        *(f32x4*)p       = y0;
        *(f32x4*)(p + 4) = y1;
      }
    }
    *(bf16x8*)(outb + (size_t)r * Npad + c) = o;
  }
}

// ---------------- reparametrize: mu/logvar/z f32 out + z bf16 (padded) ----------------
__global__ void k_reparam(const bf16_t* __restrict__ p, const float* __restrict__ sc,
                          const float* __restrict__ sh, const float* __restrict__ eps,
                          float* __restrict__ z, float* __restrict__ mu,
                          float* __restrict__ lv, bf16_t* __restrict__ zb)
{
  const long total = (long)B_ROWS * (LTP / 4);
  for (long idx = (long)blockIdx.x * blockDim.x + threadIdx.x; idx < total;
       idx += (long)gridDim.x * blockDim.x) {
    const int r = (int)(idx / (LTP / 4));
    const int j = (int)(idx % (LTP / 4)) * 4;
    if (j < LT) {                       // LT % 4 == 0
      bf16x4 pm = *(const bf16x4*)(p + (size_t)r * H2P + j);
      bf16x4 pl = *(const bf16x4*)(p + (size_t)r * H2P + LT + j);
      f32x4  e  = *(const f32x4*)(eps + (size_t)r * LT + j);
      f32x4 mv, lvv, zv; bf16x4 z4;
#pragma unroll
      for (int t = 0; t < 4; ++t) {
        float m_ = (float)pm[t] * sc[j + t] + sh[j + t];
        float l_ = (float)pl[t] * sc[LT + j + t] + sh[LT + j + t];
        float zz = fmaf(expf(l_ * 0.5f), e[t], m_);
        mv[t] = m_; lvv[t] = l_; zv[t] = zz; z4[t] = (bf16_t)zz;
      }
      *(f32x4*)(mu + (size_t)r * LT + j) = mv;
      *(f32x4*)(lv + (size_t)r * LT + j) = lvv;
      *(f32x4*)(z  + (size_t)r * LT + j) = zv;
      *(bf16x4*)(zb + (size_t)r * LTP + j) = z4;
    } else {
      bf16x4 z4;
#pragma unroll
      for (int t = 0; t < 4; ++t) z4[t] = (bf16_t)0.f;
      *(bf16x4*)(zb + (size_t)r * LTP + j) = z4;
    }
  }
}

// ---------------- host ----------------
extern "C" void kernel_launch(void* const* d_in, const int* in_sizes, int n_in,
                              void* d_out, int out_size, void* d_ws, size_t ws_size,
                              hipStream_t stream)
{
  const float* x     = (const float*)d_in[0];
  const float* eps   = (const float*)d_in[1];
  const float* mask1 = (const float*)d_in[2];
  const float* mask2 = (const float*)d_in[3];
  const float* maskd = (const float*)d_in[4];
  const float* maskm = (const float*)d_in[5];
  const float* W1    = (const float*)d_in[6];
  // b1 (d_in[7]) cancels in BN (mean subtraction) -> unused
  const float* g1    = (const float*)d_in[8];
  const float* be1   = (const float*)d_in[9];
  const float* W2    = (const float*)d_in[10];
  // b2 (d_in[11]) cancels in BN
  const float* g2    = (const float*)d_in[12];
  const float* be2   = (const float*)d_in[13];
  const float* Wd    = (const float*)d_in[14];
  // bd (d_in[15]) cancels in BN
  const float* gd    = (const float*)d_in[16];
  const float* bed   = (const float*)d_in[17];
  const float* Wm    = (const float*)d_in[18];
  float* out = (float*)d_out;
  char*  ws  = (char*)d_ws;

  // workspace layout (aliased where lifetimes are disjoint)
  size_t off = 0;
  auto alloc = [&](size_t bytes) { size_t o = off; off += (bytes + 255) & ~(size_t)255; return o; };
  const size_t XBF  = alloc((size_t)B_ROWS * GENP * 2);  // x bf16; later mo_bf16
  const size_t W1M  = alloc((size_t)H1P * GENP * 2);     // W1 masked; later p_pre
  const size_t W2M  = alloc((size_t)H2P * H1P * 2);
  const size_t WDM  = alloc((size_t)H1P * LTP * 2);
  const size_t WMM  = alloc((size_t)GENP * H1P * 2);
  const size_t HPRE = alloc((size_t)B_ROWS * H1P * 2);   // h_pre; later d_pre
  const size_t HBF  = alloc((size_t)B_ROWS * H1P * 2);   // h bf16; later z bf16
  const size_t STAT = alloc((size_t)(H1P + H2P + H1P) * 2 * sizeof(float));
  if (ws_size < off) {
    fprintf(stderr, "kernel_launch: workspace too small: need %zu have %zu\n", off, ws_size);
    return;
  }

  bf16_t* xb   = (bf16_t*)(ws + XBF);
  bf16_t* w1m  = (bf16_t*)(ws + W1M);
  bf16_t* w2m  = (bf16_t*)(ws + W2M);
  bf16_t* wdm  = (bf16_t*)(ws + WDM);
  bf16_t* wmm  = (bf16_t*)(ws + WMM);
  bf16_t* hpre = (bf16_t*)(ws + HPRE);
  bf16_t* hbf  = (bf16_t*)(ws + HBF);
  bf16_t* ppre = (bf16_t*)(ws + W1M);   // alias: W1 masked dead after GEMM1
  bf16_t* zbf  = (bf16_t*)(ws + HBF);   // alias: h bf16 dead after GEMM2
  bf16_t* dpre = (bf16_t*)(ws + HPRE);  // alias: h_pre dead after BN1 apply
  bf16_t* mobf = (bf16_t*)(ws + XBF);   // alias: x bf16 dead after GEMM1

  float* s1 = (float*)(ws + STAT);
  float* q1 = s1 + H1P;
  float* s2 = q1 + H1P;
  float* q2 = s2 + H2P;
  float* sd = q2 + H2P;
  float* qd = sd + H1P;

  float* o_recon = out;
  float* o_z     = o_recon + (size_t)B_ROWS * GEN;
  float* o_mo    = o_z     + (size_t)B_ROWS * LT;
  float* o_mu    = o_mo    + (size_t)B_ROWS * H1;
  float* o_lv    = o_mu    + (size_t)B_ROWS * LT;

  hipMemsetAsync(ws + STAT, 0, (size_t)(H1P + H2P + H1P) * 2 * sizeof(float), stream);

  // prep: cast/mask to bf16, zero-padded
  k_prep<<<2048, 256, 0, stream>>>(x,  nullptr, xb,  B_ROWS, GEN, B_ROWS, GENP);
  k_prep<<<2048, 256, 0, stream>>>(W1, mask1,   w1m, H1,  GEN, H1P,  GENP);
  k_prep<<<2048, 256, 0, stream>>>(W2, mask2,   w2m, H2,  H1,  H2P,  H1P);
  k_prep<<<2048, 256, 0, stream>>>(Wd, maskd,   wdm, H1,  LT,  H1P,  LTP);
  k_prep<<<2048, 256, 0, stream>>>(Wm, maskm,   wmm, GEN, H1,  GENP, H1P);

  // encoder L1: h_pre = x @ W1m^T  (+ batch stats)
  gemm_bt<0><<<dim3(H1P / 128, B_ROWS / 128), 256, 0, stream>>>(
      xb, w1m, GENP, hpre, H1P, s1, q1, nullptr, 0);
  k_finalize<<<(H1P + 255) / 256, 256, 0, stream>>>(s1, q1, g1, be1, H1, H1P);
  k_bn_elu<<<2048, 256, 0, stream>>>(hpre, s1, q1, hbf, nullptr, H1, H1P, 1);

  // encoder L2: p_pre = h @ W2m^T (+ stats), then reparametrize
  gemm_bt<0><<<dim3(H2P / 128, B_ROWS / 128), 256, 0, stream>>>(
      hbf, w2m, H1P, ppre, H2P, s2, q2, nullptr, 0);
  k_finalize<<<(H2P + 255) / 256, 256, 0, stream>>>(s2, q2, g2, be2, H2, H2P);
  k_reparam<<<2048, 256, 0, stream>>>(ppre, s2, q2, eps, o_z, o_mu, o_lv, zbf);

  // decoder: d_pre = z @ Wdm^T (+ stats), BN+ELU -> module_outputs
  gemm_bt<0><<<dim3(H1P / 128, B_ROWS / 128), 256, 0, stream>>>(
      zbf, wdm, LTP, dpre, H1P, sd, qd, nullptr, 0);
  k_finalize<<<(H1P + 255) / 256, 256, 0, stream>>>(sd, qd, gd, bed, H1, H1P);
  k_bn_elu<<<2048, 256, 0, stream>>>(dpre, sd, qd, mobf, o_mo, H1, H1P, 1);

  // merger: global_recon = mo @ Wmm^T (f32 out, no BN)
  gemm_bt<1><<<dim3(GENP / 128, B_ROWS / 128), 256, 0, stream>>>(
      mobf, wmm, H1P, nullptr, 0, nullptr, nullptr, o_recon, GEN);
}

// Round 2
// 1577.770 us; speedup vs baseline: 1.1106x; 1.1106x over previous
//
#include <hip/hip_runtime.h>
#include <cstdio>
#include <cstdint>

typedef __bf16 bf16_t;
typedef __bf16 bf16x8 __attribute__((ext_vector_type(8)));
typedef __bf16 bf16x4 __attribute__((ext_vector_type(4)));
typedef float  f32x4  __attribute__((ext_vector_type(4)));

// problem dims
#define B_ROWS 8192
#define GEN    5000
#define GENP   5120   // padded K for gemm1 / N for gemm_m
#define H1     4128
#define H1P    4224
#define H2     2064
#define H2P    2176
#define LT     1032
#define LTP    1152

// ---------------- async global->LDS helper ----------------
__device__ __forceinline__ void load_lds16(const bf16_t* g, bf16_t* l) {
  __builtin_amdgcn_global_load_lds((__attribute__((address_space(1))) void*)g,
                                   (__attribute__((address_space(3))) void*)l,
                                   16, 0, 0);
}

// ---------------- GEMM: C = A (MxK) * B^T (NxK), bf16 in, f32 acc ----------------
// LDS layout: linear [128][64] per matrix, but element (r, granule gl) holds
// global data (r, granule gl ^ (r&7))  [T2 XOR-swizzle via pre-swizzled global
// source, rule #21: linear dest + inverse-swz source + swz on read]
// MODE 0: store C as bf16 (ld Npad) + atomic per-column sum/sumsq (for BN stats)
// MODE 1: store C as f32 to Cf with column bound Nvalid (ld Nvalid)
template<int MODE>
__global__ __launch_bounds__(256, 2)
void gemm_bt(const bf16_t* __restrict__ A, const bf16_t* __restrict__ Bm,
             int K, bf16_t* __restrict__ Cb, int Npad,
             float* __restrict__ sum, float* __restrict__ sq,
             float* __restrict__ Cf, int Nvalid)
{
  __shared__ bf16_t As[128 * 64];
  __shared__ bf16_t Bs[128 * 64];
  const int tid  = threadIdx.x;
  const int wave = tid >> 6;
  const int lane = tid & 63;

  // T1: bijective XCD-aware block swizzle (m204)
  const int nwg = gridDim.x * gridDim.y;
  int wg = blockIdx.y * gridDim.x + blockIdx.x;
  {
    const int q = nwg >> 3, r8 = nwg & 7;
    const int xcd = wg & 7, sidx = wg >> 3;
    wg = (xcd < r8 ? xcd * (q + 1) : r8 * (q + 1) + (xcd - r8) * q) + sidx;
  }
  const int brow = (wg / gridDim.x) * 128;
  const int bcol = (wg % gridDim.x) * 128;

  const int wrow = (wave >> 1) * 64;
  const int wcol = (wave & 1) * 64;

  // staging: 8 threads per 64-elem row, 16B per thread; granule XOR-swizzled
  const int rr  = tid >> 3;                         // 0..31
  const int cc  = (((tid & 7) ^ (rr & 7)) << 3);    // swizzled 8-elem granule

  const bf16_t* ga[4];
  const bf16_t* gb[4];
#pragma unroll
  for (int i = 0; i < 4; ++i) {
    ga[i] = A  + (size_t)(brow + i * 32 + rr) * K + cc;
    gb[i] = Bm + (size_t)(bcol + i * 32 + rr) * K + cc;
  }
  bf16_t* lab = As + wave * 512;  // wave-uniform LDS base (lane*16B appended by HW)
  bf16_t* lbb = Bs + wave * 512;

  f32x4 acc[4][4] = {};

  const int lr  = lane & 15;
  const int g0  = lane >> 4;       // granule sub-index 0..3
  const int rsw = lr & 7;          // read-side swizzle key (row & 7)

  for (int kt = 0; kt < K; kt += 64) {
#pragma unroll
    for (int i = 0; i < 4; ++i) {
      load_lds16(ga[i] + kt, lab + i * 2048);
      load_lds16(gb[i] + kt, lbb + i * 2048);
    }
    __syncthreads();
#pragma unroll
    for (int kk = 0; kk < 2; ++kk) {
      const int swz = (((kk * 4 + g0) ^ rsw) << 3);  // swizzled element offset in row
      bf16x8 af[4], bfr[4];
#pragma unroll
      for (int mi = 0; mi < 4; ++mi)
        af[mi] = *(const bf16x8*)(As + (wrow + mi * 16 + lr) * 64 + swz);
#pragma unroll
      for (int ni = 0; ni < 4; ++ni)
        bfr[ni] = *(const bf16x8*)(Bs + (wcol + ni * 16 + lr) * 64 + swz);
#pragma unroll
      for (int mi = 0; mi < 4; ++mi)
#pragma unroll
        for (int ni = 0; ni < 4; ++ni)
          acc[mi][ni] = __builtin_amdgcn_mfma_f32_16x16x32_bf16(af[mi], bfr[ni], acc[mi][ni], 0, 0, 0);
    }
    __syncthreads();
  }

  // epilogue: C/D layout col=lane&15, row=(lane>>4)*4+reg  [guide §3, m89-verified]
  const int lcol = lane & 15;
  const int lrow = (lane >> 4) * 4;
  if (MODE == 0) {
#pragma unroll
    for (int ni = 0; ni < 4; ++ni) {
      const int colg = bcol + wcol + ni * 16 + lcol;
      float s = 0.f, s2 = 0.f;
#pragma unroll
      for (int mi = 0; mi < 4; ++mi) {
        const int rowg = brow + wrow + mi * 16 + lrow;
#pragma unroll
        for (int r = 0; r < 4; ++r) {
          float v = acc[mi][ni][r];
          s += v; s2 += v * v;
          Cb[(size_t)(rowg + r) * Npad + colg] = (bf16_t)v;
        }
      }
      // reduce over the 4 lane-groups sharing this column (rows of the 64-row wave tile)
      s  += __shfl_xor(s, 16, 64);  s  += __shfl_xor(s, 32, 64);
      s2 += __shfl_xor(s2, 16, 64); s2 += __shfl_xor(s2, 32, 64);
      if (lane < 16) {
        atomicAdd(&sum[colg], s);
        atomicAdd(&sq[colg], s2);
      }
    }
  } else {
#pragma unroll
    for (int ni = 0; ni < 4; ++ni) {
      const int colg = bcol + wcol + ni * 16 + lcol;
      if (colg < Nvalid) {
#pragma unroll
        for (int mi = 0; mi < 4; ++mi) {
          const int rowg = brow + wrow + mi * 16 + lrow;
#pragma unroll
          for (int r = 0; r < 4; ++r)
            Cf[(size_t)(rowg + r) * Nvalid + colg] = acc[mi][ni][r];
        }
      }
    }
  }
}

// ---------------- prep: out[npad][kpad] = bf16(W*mask), zero-padded ----------------
__global__ void k_prep(const float* __restrict__ W, const float* __restrict__ Mk,
                       bf16_t* __restrict__ out, int N, int K, int Npad, int Kpad)
{
  const int  kg    = Kpad >> 3;
  const long total = (long)Npad * kg;
  for (long idx = (long)blockIdx.x * blockDim.x + threadIdx.x; idx < total;
       idx += (long)gridDim.x * blockDim.x) {
    const int n = (int)(idx / kg);
    const int c = (int)(idx % kg) * 8;
    bf16x8 o;
#pragma unroll
    for (int j = 0; j < 8; ++j) o[j] = (bf16_t)0.f;
    if (n < N && c < K) {               // K % 8 == 0 for all inputs
      const f32x4* w4 = (const f32x4*)(W + (size_t)n * K + c);
      f32x4 a = w4[0], b = w4[1];
      if (Mk) {
        const f32x4* m4 = (const f32x4*)(Mk + (size_t)n * K + c);
        f32x4 ma = m4[0], mb = m4[1];
        a *= ma; b *= mb;
      }
#pragma unroll
      for (int j = 0; j < 4; ++j) { o[j] = (bf16_t)a[j]; o[4 + j] = (bf16_t)b[j]; }
    }
    *(bf16x8*)(out + (size_t)idx * 8) = o;
  }
}

// ---------------- BN finalize: sum->scale, sq->shift ----------------
__global__ void k_finalize(float* __restrict__ sum, float* __restrict__ sq,
                           const float* __restrict__ g, const float* __restrict__ be,
                           int Nvalid, int Npad)
{
  const int c = blockIdx.x * blockDim.x + threadIdx.x;
  if (c >= Npad) return;
  float sc = 0.f, sh = 0.f;
  if (c < Nvalid) {
    const float invM = 1.0f / 8192.0f;
    float mean = sum[c] * invM;
    float var  = sq[c] * invM - mean * mean;
    sc = g[c] * rsqrtf(var + 1e-3f);
    sh = be[c] - mean * sc;
  }
  sum[c] = sc; sq[c] = sh;
}

// ---------------- BN apply (+optional ELU, optional f32 out) ----------------
__global__ void k_bn_elu(const bf16_t* __restrict__ pre, const float* __restrict__ sc,
                         const float* __restrict__ sh, bf16_t* __restrict__ outb,
                         float* __restrict__ outf, int Nvalid, int Npad, int elu)
{
  const int  ng    = Npad >> 3;
  const long total = (long)B_ROWS * ng;
  for (long idx = (long)blockIdx.x * blockDim.x + threadIdx.x; idx < total;
       idx += (long)gridDim.x * blockDim.x) {
    const int r = (int)(idx / ng);
    const int c = (int)(idx % ng) * 8;
    bf16x8 o;
#pragma unroll
    for (int j = 0; j < 8; ++j) o[j] = (bf16_t)0.f;
    if (c < Nvalid) {                   // Nvalid % 8 == 0 -> group fully valid
      bf16x8 x = *(const bf16x8*)(pre + (size_t)r * Npad + c);
      f32x4 y0, y1;
#pragma unroll
      for (int j = 0; j < 8; ++j) {
        float v = (float)x[j] * sc[c + j] + sh[c + j];
        if (elu) v = v > 0.f ? v : expm1f(v);
        if (j < 4) y0[j] = v; else y1[j - 4] = v;
        o[j] = (bf16_t)v;
      }
      if (outf) {
        float* p = outf + (size_t)r * Nvalid + c;
        *(f32x4*)p       = y0;
        *(f32x4*)(p + 4) = y1;
      }
    }
    *(bf16x8*)(outb + (size_t)r * Npad + c) = o;
  }
}

// ---------------- reparametrize: mu/logvar/z f32 out + z bf16 (padded) ----------------
__global__ void k_reparam(const bf16_t* __restrict__ p, const float* __restrict__ sc,
                          const float* __restrict__ sh, const float* __restrict__ eps,
                          float* __restrict__ z, float* __restrict__ mu,
                          float* __restrict__ lv, bf16_t* __restrict__ zb)
{
  const long total = (long)B_ROWS * (LTP / 4);
  for (long idx = (long)blockIdx.x * blockDim.x + threadIdx.x; idx < total;
       idx += (long)gridDim.x * blockDim.x) {
    const int r = (int)(idx / (LTP / 4));
    const int j = (int)(idx % (LTP / 4)) * 4;
    if (j < LT) {                       // LT % 4 == 0
      bf16x4 pm = *(const bf16x4*)(p + (size_t)r * H2P + j);
      bf16x4 pl = *(const bf16x4*)(p + (size_t)r * H2P + LT + j);
      f32x4  e  = *(const f32x4*)(eps + (size_t)r * LT + j);
      f32x4 mv, lvv, zv; bf16x4 z4;
#pragma unroll
      for (int t = 0; t < 4; ++t) {
        float m_ = (float)pm[t] * sc[j + t] + sh[j + t];
        float l_ = (float)pl[t] * sc[LT + j + t] + sh[LT + j + t];
        float zz = fmaf(expf(l_ * 0.5f), e[t], m_);
        mv[t] = m_; lvv[t] = l_; zv[t] = zz; z4[t] = (bf16_t)zz;
      }
      *(f32x4*)(mu + (size_t)r * LT + j) = mv;
      *(f32x4*)(lv + (size_t)r * LT + j) = lvv;
      *(f32x4*)(z  + (size_t)r * LT + j) = zv;
      *(bf16x4*)(zb + (size_t)r * LTP + j) = z4;
    } else {
      bf16x4 z4;
#pragma unroll
      for (int t = 0; t < 4; ++t) z4[t] = (bf16_t)0.f;
      *(bf16x4*)(zb + (size_t)r * LTP + j) = z4;
    }
  }
}

// ---------------- host ----------------
extern "C" void kernel_launch(void* const* d_in, const int* in_sizes, int n_in,
                              void* d_out, int out_size, void* d_ws, size_t ws_size,
                              hipStream_t stream)
{
  const float* x     = (const float*)d_in[0];
  const float* eps   = (const float*)d_in[1];
  const float* mask1 = (const float*)d_in[2];
  const float* mask2 = (const float*)d_in[3];
  const float* maskd = (const float*)d_in[4];
  const float* maskm = (const float*)d_in[5];
  const float* W1    = (const float*)d_in[6];
  // b1 (d_in[7]) cancels in BN (mean subtraction) -> unused
  const float* g1    = (const float*)d_in[8];
  const float* be1   = (const float*)d_in[9];
  const float* W2    = (const float*)d_in[10];
  // b2 (d_in[11]) cancels in BN
  const float* g2    = (const float*)d_in[12];
  const float* be2   = (const float*)d_in[13];
  const float* Wd    = (const float*)d_in[14];
  // bd (d_in[15]) cancels in BN
  const float* gd    = (const float*)d_in[16];
  const float* bed   = (const float*)d_in[17];
  const float* Wm    = (const float*)d_in[18];
  float* out = (float*)d_out;
  char*  ws  = (char*)d_ws;

  // workspace layout (aliased where lifetimes are disjoint)
  size_t off = 0;
  auto alloc = [&](size_t bytes) { size_t o = off; off += (bytes + 255) & ~(size_t)255; return o; };
  const size_t XBF  = alloc((size_t)B_ROWS * GENP * 2);  // x bf16; later mo_bf16
  const size_t W1M  = alloc((size_t)H1P * GENP * 2);     // W1 masked; later p_pre
  const size_t W2M  = alloc((size_t)H2P * H1P * 2);
  const size_t WDM  = alloc((size_t)H1P * LTP * 2);
  const size_t WMM  = alloc((size_t)GENP * H1P * 2);
  const size_t HPRE = alloc((size_t)B_ROWS * H1P * 2);   // h_pre; later d_pre
  const size_t HBF  = alloc((size_t)B_ROWS * H1P * 2);   // h bf16; later z bf16
  const size_t STAT = alloc((size_t)(H1P + H2P + H1P) * 2 * sizeof(float));
  if (ws_size < off) {
    fprintf(stderr, "kernel_launch: workspace too small: need %zu have %zu\n", off, ws_size);
    return;
  }

  bf16_t* xb   = (bf16_t*)(ws + XBF);
  bf16_t* w1m  = (bf16_t*)(ws + W1M);
  bf16_t* w2m  = (bf16_t*)(ws + W2M);
  bf16_t* wdm  = (bf16_t*)(ws + WDM);
  bf16_t* wmm  = (bf16_t*)(ws + WMM);
  bf16_t* hpre = (bf16_t*)(ws + HPRE);
  bf16_t* hbf  = (bf16_t*)(ws + HBF);
  bf16_t* ppre = (bf16_t*)(ws + W1M);   // alias: W1 masked dead after GEMM1
  bf16_t* zbf  = (bf16_t*)(ws + HBF);   // alias: h bf16 dead after GEMM2
  bf16_t* dpre = (bf16_t*)(ws + HPRE);  // alias: h_pre dead after BN1 apply
  bf16_t* mobf = (bf16_t*)(ws + XBF);   // alias: x bf16 dead after GEMM1

  float* s1 = (float*)(ws + STAT);
  float* q1 = s1 + H1P;
  float* s2 = q1 + H1P;
  float* q2 = s2 + H2P;
  float* sd = q2 + H2P;
  float* qd = sd + H1P;

  float* o_recon = out;
  float* o_z     = o_recon + (size_t)B_ROWS * GEN;
  float* o_mo    = o_z     + (size_t)B_ROWS * LT;
  float* o_mu    = o_mo    + (size_t)B_ROWS * H1;
  float* o_lv    = o_mu    + (size_t)B_ROWS * LT;

  hipMemsetAsync(ws + STAT, 0, (size_t)(H1P + H2P + H1P) * 2 * sizeof(float), stream);

  // prep: cast/mask to bf16, zero-padded
  k_prep<<<2048, 256, 0, stream>>>(x,  nullptr, xb,  B_ROWS, GEN, B_ROWS, GENP);
  k_prep<<<2048, 256, 0, stream>>>(W1, mask1,   w1m, H1,  GEN, H1P,  GENP);
  k_prep<<<2048, 256, 0, stream>>>(W2, mask2,   w2m, H2,  H1,  H2P,  H1P);
  k_prep<<<2048, 256, 0, stream>>>(Wd, maskd,   wdm, H1,  LT,  H1P,  LTP);
  k_prep<<<2048, 256, 0, stream>>>(Wm, maskm,   wmm, GEN, H1,  GENP, H1P);

  // encoder L1: h_pre = x @ W1m^T  (+ batch stats)
  gemm_bt<0><<<dim3(H1P / 128, B_ROWS / 128), 256, 0, stream>>>(
      xb, w1m, GENP, hpre, H1P, s1, q1, nullptr, 0);
  k_finalize<<<(H1P + 255) / 256, 256, 0, stream>>>(s1, q1, g1, be1, H1, H1P);
  k_bn_elu<<<2048, 256, 0, stream>>>(hpre, s1, q1, hbf, nullptr, H1, H1P, 1);

  // encoder L2: p_pre = h @ W2m^T (+ stats), then reparametrize
  gemm_bt<0><<<dim3(H2P / 128, B_ROWS / 128), 256, 0, stream>>>(
      hbf, w2m, H1P, ppre, H2P, s2, q2, nullptr, 0);
  k_finalize<<<(H2P + 255) / 256, 256, 0, stream>>>(s2, q2, g2, be2, H2, H2P);
  k_reparam<<<2048, 256, 0, stream>>>(ppre, s2, q2, eps, o_z, o_mu, o_lv, zbf);

  // decoder: d_pre = z @ Wdm^T (+ stats), BN+ELU -> module_outputs
  gemm_bt<0><<<dim3(H1P / 128, B_ROWS / 128), 256, 0, stream>>>(
      zbf, wdm, LTP, dpre, H1P, sd, qd, nullptr, 0);
  k_finalize<<<(H1P + 255) / 256, 256, 0, stream>>>(sd, qd, gd, bed, H1, H1P);
  k_bn_elu<<<2048, 256, 0, stream>>>(dpre, sd, qd, mobf, o_mo, H1, H1P, 1);

  // merger: global_recon = mo @ Wmm^T (f32 out, no BN)
  gemm_bt<1><<<dim3(GENP / 128, B_ROWS / 128), 256, 0, stream>>>(
      mobf, wmm, H1P, nullptr, 0, nullptr, nullptr, o_recon, GEN);
}